// Round 7
// baseline (3366.750 us; speedup 1.0000x reference)
//
#include <hip/hip_runtime.h>

// SNN 2048->2048->2048->512, T=100, batch 32, LIF.
// PHASE PATH (needs ~39.3MB ws): 4 sequential launches, stream order = sync.
//   encode: Poisson spikes -> spk0 (fp16, MFMA-B-frag blocked layout)
//   layer k: per block 32 neurons x 32 batch, weights in LDS (A-frag, 128KB),
//            local t-loop 0..99, LIF in registers, no inter-block deps.
// FALLBACK (ws < needed): round-6 persistent pipeline kernel (proven 1.48ms).
#define T_STEPS 100

typedef _Float16 half8_t __attribute__((ext_vector_type(8)));
typedef _Float16 half4_t __attribute__((ext_vector_type(4)));
typedef float    f32x4   __attribute__((ext_vector_type(4)));

// ---------------- phase-path layouts ----------------
// spike buffer per interface: [t][h][idx16], h = batch half (16 batches)
//   idx16(k, b16) = (k>>3)*128 + b16*8 + (k&7)      (halves; 32768 per (t,h))
// B-frag load: wave offset (kb*4+quad)*128 + mi*8 -> B[k=kb*32+quad*8+j][n=mi]
#define SLICE_H   32768                       // halves per (t,h)
#define SPKBUF_B  (100 * 2 * SLICE_H * 2)     // 13,107,200 bytes per interface
#define PHASE_WS_NEED (3 * (size_t)SPKBUF_B)  // 39,321,600

// ---------------- encode kernel (phase path) ----------------
__global__ void snn_encode_kernel(const float* __restrict__ x,
                                  const float* __restrict__ noise,
                                  _Float16* __restrict__ spk0,
                                  float* __restrict__ out)
{
    const int gid = blockIdx.x * 256 + threadIdx.x;   // [0, 819200)
    if (gid == 0) out[16384] = 0.0f;                  // zero total_spikes slot
    const int o = gid & 255;          // feature octet (8 k)
    const int b = (gid >> 8) & 31;    // batch
    const int t = gid >> 13;          // time
    const float* xp = x + b * 2048 + o * 8;
    const float* np = noise + (size_t)t * 65536 + b * 2048 + o * 8;
    const float4 x1 = *(const float4*)(xp);
    const float4 x2 = *(const float4*)(xp + 4);
    const float4 n1 = *(const float4*)(np);
    const float4 n2 = *(const float4*)(np + 4);
    const float xr[8] = {x1.x,x1.y,x1.z,x1.w,x2.x,x2.y,x2.z,x2.w};
    const float nz[8] = {n1.x,n1.y,n1.z,n1.w,n2.x,n2.y,n2.z,n2.w};
    half8_t sp;
    #pragma unroll
    for (int j = 0; j < 8; ++j) {
        const float r = fminf(fmaxf(xr[j], 0.0f), 1.0f);
        sp[j] = (nz[j] < r) ? (_Float16)1.0f : (_Float16)0.0f;
    }
    const size_t idx = ((size_t)t * 2 + (b >> 4)) * SLICE_H + o * 128 + (b & 15) * 8;
    *(half8_t*)(spk0 + idx) = sp;
}

// ---------------- layer kernel (phase path) ----------------
// grid = n_rows/32 blocks, 128 threads (2 waves = 2 batch halves).
__global__ __launch_bounds__(128, 1) void snn_layer_kernel(
    const float* __restrict__ Wp, const float* __restrict__ bp,
    const _Float16* __restrict__ inbuf, _Float16* __restrict__ outbuf,
    float* __restrict__ out, const int is_last)
{
    const int tid  = threadIdx.x;
    const int h    = tid >> 6;          // wave = batch half
    const int lane = tid & 63;
    const int quad = lane >> 4;
    const int mi   = lane & 15;
    const int row_base = blockIdx.x * 32;

    __shared__ _Float16 wlds[32 * 2048];   // 128 KB, A-frag blocked

    // stage weights: coalesced global reads, A-frag scattered LDS stores
    // wlds[((s*64+kb)*64 + q*16 + m)*8 + j] = W[row_base+s*16+m][kb*32+q*8+j]
    for (int e = tid; e < 8192; e += 128) {
        const int r  = e >> 8;             // local row 0..31
        const int k0 = (e & 255) * 8;      // feature 0..2040
        const float* wp = Wp + (size_t)(row_base + r) * 2048 + k0;
        const float4 f1 = *(const float4*)(wp);
        const float4 f2 = *(const float4*)(wp + 4);
        half8_t hv = {(_Float16)f1.x, (_Float16)f1.y, (_Float16)f1.z, (_Float16)f1.w,
                      (_Float16)f2.x, (_Float16)f2.y, (_Float16)f2.z, (_Float16)f2.w};
        const int s  = r >> 4, m = r & 15;
        const int kb = k0 >> 5, q2 = (k0 >> 3) & 3;
        *(half8_t*)(wlds + ((size_t)((s * 64 + kb) * 64 + q2 * 16 + m)) * 8) = hv;
    }
    __syncthreads();

    float bias[2][4];
    #pragma unroll
    for (int s = 0; s < 2; ++s)
        #pragma unroll
        for (int r = 0; r < 4; ++r)
            bias[s][r] = bp[row_base + s * 16 + quad * 4 + r];

    float mem[2][4] = {{0,0,0,0},{0,0,0,0}};
    float syn[2][4] = {{0,0,0,0},{0,0,0,0}};
    float osum[2][4] = {{0,0,0,0},{0,0,0,0}};
    float cnt = 0.f;

    const _Float16* wl0 = wlds;            // subtile 0 (rows 0-15)
    const _Float16* wl1 = wlds + 64 * 512; // subtile 1 (rows 16-31): (1*64)*64*8

    for (int t = 0; t < T_STEPS; ++t) {
        const _Float16* bbase = inbuf + ((size_t)t * 2 + h) * SLICE_H;
        f32x4 aA0 = {0,0,0,0}, aB0 = {0,0,0,0};   // subtile 0, 2 chains
        f32x4 aA1 = {0,0,0,0}, aB1 = {0,0,0,0};   // subtile 1, 2 chains
        #pragma unroll 4
        for (int kb = 0; kb < 64; kb += 2) {
            const half8_t bf0 = *(const half8_t*)(bbase + (kb * 4 + quad) * 128 + mi * 8);
            const half8_t bf1 = *(const half8_t*)(bbase + ((kb + 1) * 4 + quad) * 128 + mi * 8);
            const half8_t a00 = *(const half8_t*)(wl0 + ((size_t)(kb * 64 + lane)) * 8);
            const half8_t a01 = *(const half8_t*)(wl1 + ((size_t)(kb * 64 + lane)) * 8);
            const half8_t a10 = *(const half8_t*)(wl0 + ((size_t)((kb + 1) * 64 + lane)) * 8);
            const half8_t a11 = *(const half8_t*)(wl1 + ((size_t)((kb + 1) * 64 + lane)) * 8);
            aA0 = __builtin_amdgcn_mfma_f32_16x16x32_f16(a00, bf0, aA0, 0, 0, 0);
            aA1 = __builtin_amdgcn_mfma_f32_16x16x32_f16(a01, bf0, aA1, 0, 0, 0);
            aB0 = __builtin_amdgcn_mfma_f32_16x16x32_f16(a10, bf1, aB0, 0, 0, 0);
            aB1 = __builtin_amdgcn_mfma_f32_16x16x32_f16(a11, bf1, aB1, 0, 0, 0);
        }
        const f32x4 acc0 = aA0 + aB0;
        const f32x4 acc1 = aA1 + aB1;
        // LIF: C layout row = quad*4+r (neuron), col = mi (batch in half h)
        #pragma unroll
        for (int s = 0; s < 2; ++s) {
            const f32x4 a = s ? acc1 : acc0;
            half4_t pk;
            #pragma unroll
            for (int r = 0; r < 4; ++r) {
                const float I = a[r] + bias[s][r];
                syn[s][r] = syn[s][r] + (-syn[s][r] / 5.0f + I);
                mem[s][r] = mem[s][r] + (-mem[s][r] / 20.0f + syn[s][r]);
                const float sv = (mem[s][r] >= 1.0f) ? 1.0f : 0.0f;
                mem[s][r] = (sv != 0.0f) ? 0.0f : mem[s][r];
                mem[s][r] = (mem[s][r] > 0.0f) ? mem[s][r] : 0.0f;
                cnt += sv;
                osum[s][r] += sv;
                pk[r] = (_Float16)sv;
            }
            if (!is_last) {
                const int k_out = row_base + s * 16 + quad * 4;
                const size_t idx = ((size_t)t * 2 + h) * SLICE_H
                                 + (k_out >> 3) * 128 + mi * 8 + (k_out & 7);
                *(half4_t*)(outbuf + idx) = pk;
            }
        }
    }

    if (is_last) {
        #pragma unroll
        for (int s = 0; s < 2; ++s)
            #pragma unroll
            for (int r = 0; r < 4; ++r)
                out[(h * 16 + mi) * 512 + row_base + s * 16 + quad * 4 + r] =
                    osum[s][r] / 100.0f;
    }
    // total spikes: wave reduce, one atomic per wave
    float c = cnt;
    #pragma unroll
    for (int m = 1; m < 64; m <<= 1) c += __shfl_xor(c, m);
    if (lane == 0) atomicAdd(&out[16384], c);
}

// =====================================================================
// FALLBACK: round-6 persistent pipeline kernel (proven), ws <= 794,624 B
// =====================================================================
#define NBLOCKS_FB 288
#define IN_OFF  0
#define S1_OFF  131072
#define S2_OFF  262144
#define CTRL_OFF_B 786432

__device__ __forceinline__ void grid_barrier_fb(unsigned* ctrl, unsigned k) {
    __syncthreads();
    if (threadIdx.x == 0) {
        unsigned* leaf = ctrl + (blockIdx.x & 31) * 16;
        unsigned* root = ctrl + 1024;
        unsigned* gen  = ctrl + 1056;
        unsigned p = __hip_atomic_fetch_add(leaf, 1u, __ATOMIC_ACQ_REL,
                                            __HIP_MEMORY_SCOPE_AGENT);
        if (p == 9u * k - 1u) {
            unsigned q = __hip_atomic_fetch_add(root, 1u, __ATOMIC_ACQ_REL,
                                                __HIP_MEMORY_SCOPE_AGENT);
            if (q == 32u * k - 1u)
                __hip_atomic_store(gen, k, __ATOMIC_RELEASE,
                                   __HIP_MEMORY_SCOPE_AGENT);
        }
        while (__hip_atomic_load(gen, __ATOMIC_RELAXED,
                                 __HIP_MEMORY_SCOPE_AGENT) < k)
            __builtin_amdgcn_s_sleep(2);
        (void)__hip_atomic_load(gen, __ATOMIC_ACQUIRE,
                                __HIP_MEMORY_SCOPE_AGENT);
    }
    __syncthreads();
}

__global__ __launch_bounds__(256, 2) void snn_mfma_kernel_fb(
    const float* __restrict__ x, const float* __restrict__ noise,
    const float* __restrict__ W0, const float* __restrict__ b0,
    const float* __restrict__ W1, const float* __restrict__ b1,
    const float* __restrict__ W2, const float* __restrict__ b2,
    float* __restrict__ out, float* __restrict__ ws)
{
    const int blk  = blockIdx.x;
    const int tid  = threadIdx.x;
    const int w    = tid >> 6;
    const int lane = tid & 63;
    const int quad = lane >> 4;
    const int mi   = lane & 15;

    unsigned* ctrl = (unsigned*)((char*)ws + CTRL_OFF_B);
    _Float16* wsh  = (_Float16*)ws;

    int layer, row_base;
    if (blk < 128)      { layer = 0; row_base = blk * 16; }
    else if (blk < 256) { layer = 1; row_base = (blk - 128) * 16; }
    else                { layer = 2; row_base = (blk - 256) * 16; }

    const float* Wp = (layer == 0) ? W0 : (layer == 1) ? W1 : W2;
    const float* bp = (layer == 0) ? b0 : (layer == 1) ? b1 : b2;
    const _Float16* inbuf = wsh + ((layer == 0) ? IN_OFF : (layer == 1) ? S1_OFF : S2_OFF);
    _Float16* outbuf = (layer == 0) ? (wsh + S1_OFF) : (layer == 1) ? (wsh + S2_OFF) : nullptr;

    __shared__ _Float16 wlds[16 * 2048];
    __shared__ float    redf[3 * 2 * 64 * 4];
    #pragma unroll
    for (int it = 0; it < 16; ++it) {
        const int e  = tid + it * 256;
        const int m  = e & 15;
        const int k0 = (e >> 4) * 8;
        const float4 f1 = *(const float4*)(Wp + (size_t)(row_base + m) * 2048 + k0);
        const float4 f2 = *(const float4*)(Wp + (size_t)(row_base + m) * 2048 + k0 + 4);
        half8_t hh = {(_Float16)f1.x, (_Float16)f1.y, (_Float16)f1.z, (_Float16)f1.w,
                      (_Float16)f2.x, (_Float16)f2.y, (_Float16)f2.z, (_Float16)f2.w};
        *(half8_t*)(wlds + (size_t)e * 8) = hh;
    }
    __syncthreads();

    float bias[4];
    #pragma unroll
    for (int r = 0; r < 4; ++r) bias[r] = bp[row_base + quad * 4 + r];

    float rate[8];
    int enc_b = 0, enc_k0 = 0;
    if (layer == 2) {
        const int ei = (blk - 256) * 256 + tid;
        enc_b  = ei >> 8;
        enc_k0 = (ei & 255) * 8;
        const float4 x1 = *(const float4*)(x + enc_b * 2048 + enc_k0);
        const float4 x2 = *(const float4*)(x + enc_b * 2048 + enc_k0 + 4);
        rate[0]=x1.x; rate[1]=x1.y; rate[2]=x1.z; rate[3]=x1.w;
        rate[4]=x2.x; rate[5]=x2.y; rate[6]=x2.z; rate[7]=x2.w;
        #pragma unroll
        for (int j = 0; j < 8; ++j) rate[j] = fminf(fmaxf(rate[j], 0.0f), 1.0f);
    }

    float mem[2][4] = {{0,0,0,0},{0,0,0,0}};
    float syn[2][4] = {{0,0,0,0},{0,0,0,0}};
    float osum[2][4] = {{0,0,0,0},{0,0,0,0}};
    float cnt = 0.f;

    if (blk == 0 && tid == 0) out[16384] = 0.0f;

    for (int s = -1; s <= 101; ++s) {
        if (layer == 2) {
            const int tp = s + 1;
            if (tp >= 0 && tp < T_STEPS) {
                const float4 n1 = *(const float4*)(noise + (size_t)tp * 65536 + enc_b * 2048 + enc_k0);
                const float4 n2 = *(const float4*)(noise + (size_t)tp * 65536 + enc_b * 2048 + enc_k0 + 4);
                const float nz[8] = {n1.x,n1.y,n1.z,n1.w,n2.x,n2.y,n2.z,n2.w};
                half8_t sp;
                #pragma unroll
                for (int j = 0; j < 8; ++j)
                    sp[j] = (nz[j] < rate[j]) ? (_Float16)1.0f : (_Float16)0.0f;
                const int idx = (((enc_k0 >> 5) * 2 + (enc_b >> 4)) * 512)
                              + ((enc_k0 >> 3) & 3) * 128 + (enc_b & 15) * 8;
                *(half8_t*)(wsh + IN_OFF + (tp & 1) * 65536 + idx) = sp;
            }
        }

        const int t = s - layer;
        if (t >= 0 && t < T_STEPS) {
            const _Float16* sin = inbuf + (t & 1) * 65536;
            f32x4 acc0 = {0,0,0,0}, acc1 = {0,0,0,0};
            #pragma unroll
            for (int kb = 0; kb < 16; ++kb) {
                const half8_t a = *(const half8_t*)(wlds + ((w * 16 + kb) * 64 + lane) * 8);
                const int kbg = w * 16 + kb;
                const half8_t bfr0 = *(const half8_t*)(sin + (kbg * 2 + 0) * 512 + lane * 8);
                const half8_t bfr1 = *(const half8_t*)(sin + (kbg * 2 + 1) * 512 + lane * 8);
                acc0 = __builtin_amdgcn_mfma_f32_16x16x32_f16(a, bfr0, acc0, 0, 0, 0);
                acc1 = __builtin_amdgcn_mfma_f32_16x16x32_f16(a, bfr1, acc1, 0, 0, 0);
            }
            if (w > 0) {
                *(f32x4*)(redf + (((w - 1) * 2 + 0) * 64 + lane) * 4) = acc0;
                *(f32x4*)(redf + (((w - 1) * 2 + 1) * 64 + lane) * 4) = acc1;
            }
            __syncthreads();
            if (w == 0) {
                #pragma unroll
                for (int wv = 0; wv < 3; ++wv) {
                    acc0 += *(const f32x4*)(redf + ((wv * 2 + 0) * 64 + lane) * 4);
                    acc1 += *(const f32x4*)(redf + ((wv * 2 + 1) * 64 + lane) * 4);
                }
                #pragma unroll
                for (int nt = 0; nt < 2; ++nt) {
                    const f32x4 a = nt ? acc1 : acc0;
                    half4_t pk;
                    #pragma unroll
                    for (int r = 0; r < 4; ++r) {
                        const float I = a[r] + bias[r];
                        syn[nt][r] = syn[nt][r] + (-syn[nt][r] / 5.0f + I);
                        mem[nt][r] = mem[nt][r] + (-mem[nt][r] / 20.0f + syn[nt][r]);
                        const float sv = (mem[nt][r] >= 1.0f) ? 1.0f : 0.0f;
                        mem[nt][r] = (sv != 0.0f) ? 0.0f : mem[nt][r];
                        mem[nt][r] = (mem[nt][r] > 0.0f) ? mem[nt][r] : 0.0f;
                        cnt += sv;
                        pk[r] = (_Float16)sv;
                        osum[nt][r] += sv;
                    }
                    if (layer < 2) {
                        const int o_eb = row_base + quad * 4;
                        const int idx = (((o_eb >> 5) * 2 + nt) * 64
                                         + ((o_eb >> 3) & 3) * 16 + mi) * 8 + (o_eb & 7);
                        *(half4_t*)(outbuf + (t & 1) * 65536 + idx) = pk;
                    }
                }
            }
        }
        grid_barrier_fb(ctrl, (unsigned)(s + 2));
    }

    if (layer == 2 && w == 0) {
        #pragma unroll
        for (int nt = 0; nt < 2; ++nt)
            #pragma unroll
            for (int r = 0; r < 4; ++r)
                out[(nt * 16 + mi) * 512 + row_base + quad * 4 + r] = osum[nt][r] / 100.0f;
    }
    float c = cnt;
    #pragma unroll
    for (int m = 1; m < 64; m <<= 1) c += __shfl_xor(c, m);
    __shared__ float red4[4];
    if (lane == 0) red4[w] = c;
    __syncthreads();
    if (tid == 0)
        atomicAdd(&out[16384], red4[0] + red4[1] + red4[2] + red4[3]);
}

extern "C" void kernel_launch(void* const* d_in, const int* in_sizes, int n_in,
                              void* d_out, int out_size, void* d_ws, size_t ws_size,
                              hipStream_t stream) {
    // setup_inputs() dict order: x, noise, time_steps, W0, b0, W1, b1, W2, b2
    const float* x     = (const float*)d_in[0];
    const float* noise = (const float*)d_in[1];
    const float* W0 = (const float*)d_in[3];
    const float* b0 = (const float*)d_in[4];
    const float* W1 = (const float*)d_in[5];
    const float* b1 = (const float*)d_in[6];
    const float* W2 = (const float*)d_in[7];
    const float* b2 = (const float*)d_in[8];
    float* out = (float*)d_out;
    float* ws  = (float*)d_ws;

    if (ws_size >= PHASE_WS_NEED) {
        // -------- phase path: 4 sequential launches, no grid sync --------
        _Float16* spk0 = (_Float16*)d_ws;
        _Float16* spk1 = (_Float16*)((char*)d_ws + SPKBUF_B);
        _Float16* spk2 = (_Float16*)((char*)d_ws + 2 * (size_t)SPKBUF_B);
        snn_encode_kernel<<<dim3(3200), dim3(256), 0, stream>>>(x, noise, spk0, out);
        snn_layer_kernel<<<dim3(64), dim3(128), 0, stream>>>(W0, b0, spk0, spk1, out, 0);
        snn_layer_kernel<<<dim3(64), dim3(128), 0, stream>>>(W1, b1, spk1, spk2, out, 0);
        snn_layer_kernel<<<dim3(16), dim3(128), 0, stream>>>(W2, b2, spk2, nullptr, out, 1);
    } else {
        // -------- fallback: proven round-6 persistent pipeline --------
        (void)hipMemsetAsync((void*)((char*)d_ws + CTRL_OFF_B), 0, 8192, stream);
        snn_mfma_kernel_fb<<<dim3(NBLOCKS_FB), dim3(256), 0, stream>>>(
            x, noise, W0, b0, W1, b1, W2, b2, out, ws);
    }
    (void)in_sizes; (void)n_in; (void)out_size; (void)ws_size;
}

// Round 8
// 568.970 us; speedup vs baseline: 5.9173x; 5.9173x over previous
//
#include <hip/hip_runtime.h>

// SNN 2048->2048->2048->512, T=100, batch 32, LIF.
// Decomposition: the LIF recurrence is sequential in t, but the GEMM
// I[t] = spk[t] @ W^T is parallel over ALL t. So per layer: one big GEMM
// (M=3200 (=T*batch), K=2048) + one elementwise LIF scan. 7 stream-ordered
// launches, no grid sync anywhere.
//
//   encode: noise,x -> spkA                     (Poisson, B-frag layout)
//   gemm(W0, spkA -> I) ; scan(I,b0 -> spkB)
//   gemm(W1, spkB -> I) ; scan(I,b1 -> spkA)    (buffer reuse)
//   gemm(W2, spkA -> I) ; scan(I,b2 -> out)
//
// ws budget (PROVEN >= 39,321,600 B by round 7's phase path running):
//   spkA [0,13107200) | spkB [13107200,26214400) | I fp16 [26214400,39321600)
#define T_STEPS 100
#define MTOT    3200          // m = t*32 + b
#define SPKA_OFF 0
#define SPKB_OFF 13107200
#define I_OFF    26214400

typedef _Float16 half8_t __attribute__((ext_vector_type(8)));
typedef _Float16 half4_t __attribute__((ext_vector_type(4)));
typedef float    f32x4   __attribute__((ext_vector_type(4)));

// Spike layout (B-frag blocked, M-pitch 3200):
//   half_idx(k, m) = ((k>>3)*MTOT + m)*8 + (k&7)
// Wave B-frag load at ((kb*4+quad)*MTOT + m0 + mi)*8 yields
//   B[k=kb*32+quad*8+j][n=m0+mi]   (layout verified in rounds 6/7).

// ---------------- encode: Poisson spikes for all t ----------------
// 200 blocks x 256 thr; block handles 16 m's; LDS transpose for coalescing.
__global__ __launch_bounds__(256, 2) void snn_encode_kernel(
    const float* __restrict__ x, const float* __restrict__ noise,
    _Float16* __restrict__ spk0, float* __restrict__ out)
{
    if (blockIdx.x == 0 && threadIdx.x == 0) out[16384] = 0.0f; // runs first
    const int tid = threadIdx.x;
    const int m0  = blockIdx.x * 16;
    __shared__ half8_t lds[16 * 256];    // [m_loc][oct], 64 KB
    #pragma unroll
    for (int ml = 0; ml < 16; ++ml) {
        const int m = m0 + ml;
        const int t = m >> 5, b = m & 31;
        const float4 x1 = *(const float4*)(x + b * 2048 + tid * 8);
        const float4 x2 = *(const float4*)(x + b * 2048 + tid * 8 + 4);
        const float4 n1 = *(const float4*)(noise + (size_t)t * 65536 + b * 2048 + tid * 8);
        const float4 n2 = *(const float4*)(noise + (size_t)t * 65536 + b * 2048 + tid * 8 + 4);
        const float xr[8] = {x1.x,x1.y,x1.z,x1.w,x2.x,x2.y,x2.z,x2.w};
        const float nz[8] = {n1.x,n1.y,n1.z,n1.w,n2.x,n2.y,n2.z,n2.w};
        half8_t sp;
        #pragma unroll
        for (int j = 0; j < 8; ++j) {
            const float r = fminf(fmaxf(xr[j], 0.0f), 1.0f);
            sp[j] = (nz[j] < r) ? (_Float16)1.0f : (_Float16)0.0f;
        }
        lds[ml * 256 + tid] = sp;        // contiguous across lanes
    }
    __syncthreads();
    #pragma unroll
    for (int ml = 0; ml < 16; ++ml)      // thread = feature octet
        *(half8_t*)(spk0 + ((size_t)tid * MTOT + m0 + ml) * 8) = lds[ml * 256 + tid];
}

// ---------------- GEMM: I[m][N] (fp16) = spk @ W^T ----------------
// Weight-stationary: block = 32 rows, full K=2048 in 128KB LDS (A-frag).
// 512 thr = 8 waves; wave computes 2 n-subtiles x 2 m-tiles per iteration.
// Block->(chunk,nb) swizzle keeps one B-slice per XCD (L2-resident).
__global__ __launch_bounds__(512, 1) void snn_gemm_kernel(
    const float* __restrict__ Wp, const _Float16* __restrict__ spk,
    _Float16* __restrict__ I, const int N)
{
    const int tid  = threadIdx.x;
    const int lane = tid & 63;
    const int w    = tid >> 6;          // wave 0..7
    const int quad = lane >> 4, mi = lane & 15;
    int chunk, nb, n_chunks;
    if (N == 2048) {        // 64 n-blocks x 4 m-chunks = 256 blocks
        n_chunks = 4;
        chunk = (blockIdx.x & 7) >> 1;                    // XCD-pair -> chunk
        nb    = (blockIdx.x >> 3) | ((blockIdx.x & 1) << 5);
    } else {                // 16 n-blocks x 16 m-chunks = 256 blocks
        n_chunks = 16;
        chunk = blockIdx.x & 15;
        nb    = blockIdx.x >> 4;
    }
    const int row_base = nb * 32;

    __shared__ _Float16 wlds[32 * 2048];   // 128 KB, A-frag blocked
    // wlds[((s*64+kb)*64 + quad*16 + m)*8 + j] = W[row_base+s*16+m][kb*32+quad*8+j]
    for (int e = tid; e < 8192; e += 512) {
        const int r = e >> 8, oct = e & 255;
        const float* wp = Wp + (size_t)(row_base + r) * 2048 + oct * 8;
        const float4 f1 = *(const float4*)(wp);
        const float4 f2 = *(const float4*)(wp + 4);
        half8_t hv = {(_Float16)f1.x,(_Float16)f1.y,(_Float16)f1.z,(_Float16)f1.w,
                      (_Float16)f2.x,(_Float16)f2.y,(_Float16)f2.z,(_Float16)f2.w};
        const int s = r >> 4, mm = r & 15;
        const int kb = oct >> 2, q2 = oct & 3;
        *(half8_t*)(wlds + ((size_t)((s * 64 + kb) * 64 + q2 * 16 + mm)) * 8) = hv;
    }
    __syncthreads();

    const int jcount = (200 - chunk + n_chunks - 1) / n_chunks;  // m-tiles of this chunk
    for (int j = 2 * w; j < jcount; j += 16) {       // wave takes tile-pairs
        const int  mt0  = chunk + j * n_chunks;
        const bool has2 = (j + 1) < jcount;
        const int  mt1  = has2 ? (chunk + (j + 1) * n_chunks) : mt0;
        const int  m0 = mt0 * 16, m1 = mt1 * 16;
        f32x4 a00 = {0,0,0,0}, a10 = {0,0,0,0}, a01 = {0,0,0,0}, a11 = {0,0,0,0};
        #pragma unroll 8
        for (int kb = 0; kb < 64; ++kb) {
            const size_t bofs = (size_t)(kb * 4 + quad) * MTOT;
            const half8_t b0 = *(const half8_t*)(spk + (bofs + m0 + mi) * 8);
            const half8_t b1 = *(const half8_t*)(spk + (bofs + m1 + mi) * 8);
            const half8_t A0 = *(const half8_t*)(wlds + ((size_t)(kb * 64 + lane)) * 8);
            const half8_t A1 = *(const half8_t*)(wlds + ((size_t)((64 + kb) * 64 + lane)) * 8);
            a00 = __builtin_amdgcn_mfma_f32_16x16x32_f16(A0, b0, a00, 0, 0, 0);
            a10 = __builtin_amdgcn_mfma_f32_16x16x32_f16(A1, b0, a10, 0, 0, 0);
            a01 = __builtin_amdgcn_mfma_f32_16x16x32_f16(A0, b1, a01, 0, 0, 0);
            a11 = __builtin_amdgcn_mfma_f32_16x16x32_f16(A1, b1, a11, 0, 0, 0);
        }
        // C layout: row(neuron)=quad*4+r, col(m)=mi  -> I[m][N] fp16
        half4_t h0, h1, h2, h3;
        #pragma unroll
        for (int r = 0; r < 4; ++r) {
            h0[r] = (_Float16)a00[r]; h1[r] = (_Float16)a10[r];
            h2[r] = (_Float16)a01[r]; h3[r] = (_Float16)a11[r];
        }
        *(half4_t*)(I + (size_t)(m0 + mi) * N + row_base + quad * 4)      = h0;
        *(half4_t*)(I + (size_t)(m0 + mi) * N + row_base + 16 + quad * 4) = h1;
        if (has2) {
            *(half4_t*)(I + (size_t)(m1 + mi) * N + row_base + quad * 4)      = h2;
            *(half4_t*)(I + (size_t)(m1 + mi) * N + row_base + 16 + quad * 4) = h3;
        }
    }
}

// ---------------- LIF scan: sequential in t, parallel over (n,b) ----------
__global__ __launch_bounds__(256, 4) void snn_scan_kernel(
    const _Float16* __restrict__ I, const float* __restrict__ bias,
    _Float16* __restrict__ spk_out, float* __restrict__ out,
    const int nshift, const int is_last)
{
    const int gid = blockIdx.x * 256 + threadIdx.x;   // [0, 32<<nshift)
    const int N = 1 << nshift;
    const int n = gid & (N - 1);
    const int b = gid >> nshift;
    const float bi = bias[n];
    const size_t wbase = (size_t)(n >> 3) * MTOT * 8 + (n & 7);
    float mem = 0.f, syn = 0.f, osum = 0.f, cnt = 0.f;
    for (int t = 0; t < T_STEPS; ++t) {
        const int m = t * 32 + b;
        const float Iv = (float)I[(size_t)m * N + n] + bi;
        syn = syn + (-syn / 5.0f + Iv);
        mem = mem + (-mem / 20.0f + syn);
        const float sv = (mem >= 1.0f) ? 1.0f : 0.0f;
        mem = (sv != 0.0f) ? 0.0f : mem;       // reset
        mem = (mem > 0.0f) ? mem : 0.0f;       // clamp negatives
        cnt += sv; osum += sv;
        if (!is_last) spk_out[wbase + (size_t)m * 8] = (_Float16)sv;
    }
    if (is_last) out[b * 512 + n] = osum * 0.01f;    // mean over T
    float c = cnt;
    #pragma unroll
    for (int s2 = 1; s2 < 64; s2 <<= 1) c += __shfl_xor(c, s2);
    if ((threadIdx.x & 63) == 0) atomicAdd(&out[16384], c);
}

extern "C" void kernel_launch(void* const* d_in, const int* in_sizes, int n_in,
                              void* d_out, int out_size, void* d_ws, size_t ws_size,
                              hipStream_t stream) {
    // setup_inputs() dict order: x, noise, time_steps, W0, b0, W1, b1, W2, b2
    const float* x     = (const float*)d_in[0];
    const float* noise = (const float*)d_in[1];
    const float* W0 = (const float*)d_in[3];
    const float* b0 = (const float*)d_in[4];
    const float* W1 = (const float*)d_in[5];
    const float* b1 = (const float*)d_in[6];
    const float* W2 = (const float*)d_in[7];
    const float* b2 = (const float*)d_in[8];
    float* out = (float*)d_out;

    _Float16* spkA = (_Float16*)((char*)d_ws + SPKA_OFF);
    _Float16* spkB = (_Float16*)((char*)d_ws + SPKB_OFF);
    _Float16* Ibuf = (_Float16*)((char*)d_ws + I_OFF);

    snn_encode_kernel<<<dim3(200), dim3(256), 0, stream>>>(x, noise, spkA, out);

    snn_gemm_kernel<<<dim3(256), dim3(512), 0, stream>>>(W0, spkA, Ibuf, 2048);
    snn_scan_kernel<<<dim3(256), dim3(256), 0, stream>>>(Ibuf, b0, spkB, out, 11, 0);

    snn_gemm_kernel<<<dim3(256), dim3(512), 0, stream>>>(W1, spkB, Ibuf, 2048);
    snn_scan_kernel<<<dim3(256), dim3(256), 0, stream>>>(Ibuf, b1, spkA, out, 11, 0);

    snn_gemm_kernel<<<dim3(256), dim3(512), 0, stream>>>(W2, spkA, Ibuf, 512);
    snn_scan_kernel<<<dim3(64),  dim3(256), 0, stream>>>(Ibuf, b2, spkB, out, 9, 1);

    (void)in_sizes; (void)n_in; (void)out_size; (void)ws_size;
}

// Round 9
// 432.320 us; speedup vs baseline: 7.7876x; 1.3161x over previous
//
#include <hip/hip_runtime.h>

// SNN 2048->2048->2048->512, T=100, batch 32, LIF.
// Per layer: big GEMM over all t (M=3200=T*32) + sequential LIF scan.
// 10 stream-ordered launches, no grid sync.
//
// Unified buffer layout ("octet-blocked", pitch MTOT) for spikes AND I:
//   half_idx(v, m) = ((v>>3)*MTOT + m)*8 + (v&7)     v = feature index
// Wave B-frag load at ((kb*4+quad)*MTOT + m0+mi)*8 yields
//   B[k=kb*32+quad*8+j][n=m0+mi]   (layout proven rounds 6-8).
//
// ws regions (total 39,321,600 B -- PROVEN available in round 7):
//   R0 [0, 13107200)          R1 [+13107200)          R2/I [+26214400)
// Weight fp16 staging buffers live in whichever spike region is dead:
//   enc->R0 | convW0->R1 | gemm0(R0,W@R1->I) | scan0(I->R1)
//   convW1->R0 | gemm1(R1,W@R0->I) | scan1(I->R0)
//   convW2->R1 | gemm2(R0,W@R1->I) | scan2(I->out)
#define T_STEPS 100
#define MTOT    3200
#define R0_OFF  0
#define R1_OFF  13107200
#define I_OFF   26214400

typedef _Float16 half8_t __attribute__((ext_vector_type(8)));
typedef _Float16 half4_t __attribute__((ext_vector_type(4)));
typedef float    f32x4   __attribute__((ext_vector_type(4)));

// ---------------- encode: Poisson spikes for all t ----------------
__global__ __launch_bounds__(256, 2) void snn_encode_kernel(
    const float* __restrict__ x, const float* __restrict__ noise,
    _Float16* __restrict__ spk0, float* __restrict__ out)
{
    if (blockIdx.x == 0 && threadIdx.x == 0) out[16384] = 0.0f; // runs first
    const int tid = threadIdx.x;
    const int m0  = blockIdx.x * 16;
    __shared__ half8_t lds[16 * 257];    // pad 1: store-phase reads conflict-free
    #pragma unroll
    for (int ml = 0; ml < 16; ++ml) {    // read phase: thread = feature octet
        const int m = m0 + ml;
        const int t = m >> 5, b = m & 31;
        const float4 x1 = *(const float4*)(x + b * 2048 + tid * 8);
        const float4 x2 = *(const float4*)(x + b * 2048 + tid * 8 + 4);
        const float4 n1 = *(const float4*)(noise + (size_t)t * 65536 + b * 2048 + tid * 8);
        const float4 n2 = *(const float4*)(noise + (size_t)t * 65536 + b * 2048 + tid * 8 + 4);
        const float xr[8] = {x1.x,x1.y,x1.z,x1.w,x2.x,x2.y,x2.z,x2.w};
        const float nz[8] = {n1.x,n1.y,n1.z,n1.w,n2.x,n2.y,n2.z,n2.w};
        half8_t sp;
        #pragma unroll
        for (int j = 0; j < 8; ++j) {
            const float r = fminf(fmaxf(xr[j], 0.0f), 1.0f);
            sp[j] = (nz[j] < r) ? (_Float16)1.0f : (_Float16)0.0f;
        }
        lds[ml * 257 + tid] = sp;
    }
    __syncthreads();
    #pragma unroll
    for (int r = 0; r < 16; ++r) {       // store phase: lanes = consecutive m
        const int ml  = tid & 15;
        const int oct = r * 16 + (tid >> 4);
        *(half8_t*)(spk0 + ((size_t)oct * MTOT + m0 + ml) * 8) = lds[ml * 257 + oct];
    }
}

// ---------------- convert W (fp32) -> Wf (fp16, A-frag swizzled) ----------
// Wf[nb*32768 + (kb*64 + quad*16 + (row&15))*8 + j] = W[row][kb*32+quad*8+j]
__global__ __launch_bounds__(256) void snn_convw_kernel(
    const float* __restrict__ W, _Float16* __restrict__ Wf)
{
    const int row  = blockIdx.x;
    const int koct = threadIdx.x;        // 0..255
    const float* wp = W + (size_t)row * 2048 + koct * 8;
    const float4 f1 = *(const float4*)(wp);
    const float4 f2 = *(const float4*)(wp + 4);
    half8_t h = {(_Float16)f1.x,(_Float16)f1.y,(_Float16)f1.z,(_Float16)f1.w,
                 (_Float16)f2.x,(_Float16)f2.y,(_Float16)f2.z,(_Float16)f2.w};
    const size_t idx = (size_t)(row >> 4) * 32768
                     + ((size_t)((koct >> 2) * 64 + (koct & 3) * 16 + (row & 15))) * 8;
    *(half8_t*)(Wf + idx) = h;
}

// ---------------- GEMM: I = spk @ W^T (all fp16, MFMA 16x16x32) ----------
// Block: 16 N-rows (one A subtile, 64KB LDS), 512 thr = 8 waves.
// Wave: 4 m-tile accumulators per group, explicit next-kb prefetch.
// Grid: (N/16) nb x n_chunks m-chunks; chunk = blk & (nc-1) aligns chunk
// with XCD (blk%8) so each XCD's L2 holds one chunk's B slice.
template<int N, int NC>
__global__ __launch_bounds__(512, 4) void snn_gemm_kernel(
    const _Float16* __restrict__ Wf, const _Float16* __restrict__ spk,
    _Float16* __restrict__ I)
{
    const int tid  = threadIdx.x;
    const int lane = tid & 63;
    const int w    = tid >> 6;           // wave 0..7
    const int quad = lane >> 4, mi = lane & 15;
    const int chunk = blockIdx.x & (NC - 1);
    const int nb    = blockIdx.x / NC;
    const int row_base = nb * 16;
    const int jcount = (200 - chunk + NC - 1) / NC;   // m-tiles in this chunk

    __shared__ _Float16 wlds[16 * 2048];              // 64 KB, A-frag order
    {   // staging: contiguous fp16 copy (Wf pre-swizzled)
        const half8_t* __restrict__ src = (const half8_t*)(Wf + (size_t)nb * 32768);
        half8_t* __restrict__ dst = (half8_t*)wlds;
        #pragma unroll
        for (int r = 0; r < 8; ++r) dst[tid + r * 512] = src[tid + r * 512];
    }
    __syncthreads();

    for (int jl0 = 4 * w; jl0 < jcount; jl0 += 32) {
        // 4 m-tiles (clamp invalid to last; predicate stores)
        int  mt[4]; bool val[4];
        #pragma unroll
        for (int u = 0; u < 4; ++u) {
            const int jl = jl0 + u;
            val[u] = jl < jcount;
            mt[u]  = chunk + NC * (val[u] ? jl : (jcount - 1));
        }
        const _Float16* bp0 = spk + ((size_t)mt[0] * 16 + mi) * 8;
        const _Float16* bp1 = spk + ((size_t)mt[1] * 16 + mi) * 8;
        const _Float16* bp2 = spk + ((size_t)mt[2] * 16 + mi) * 8;
        const _Float16* bp3 = spk + ((size_t)mt[3] * 16 + mi) * 8;

        f32x4 acc0 = {0,0,0,0}, acc1 = {0,0,0,0}, acc2 = {0,0,0,0}, acc3 = {0,0,0,0};
        // prefetch kb=0
        size_t ko = (size_t)quad * (MTOT * 8);
        half8_t a_c  = *(const half8_t*)(wlds + (size_t)lane * 8);
        half8_t b0_c = *(const half8_t*)(bp0 + ko);
        half8_t b1_c = *(const half8_t*)(bp1 + ko);
        half8_t b2_c = *(const half8_t*)(bp2 + ko);
        half8_t b3_c = *(const half8_t*)(bp3 + ko);
        #pragma unroll 4
        for (int kb = 0; kb < 64; ++kb) {
            half8_t a_n, b0_n, b1_n, b2_n, b3_n;
            if (kb < 63) {
                const size_t kn = (size_t)((kb + 1) * 4 + quad) * (MTOT * 8);
                a_n  = *(const half8_t*)(wlds + ((size_t)(kb + 1) * 64 + lane) * 8);
                b0_n = *(const half8_t*)(bp0 + kn);
                b1_n = *(const half8_t*)(bp1 + kn);
                b2_n = *(const half8_t*)(bp2 + kn);
                b3_n = *(const half8_t*)(bp3 + kn);
            }
            acc0 = __builtin_amdgcn_mfma_f32_16x16x32_f16(a_c, b0_c, acc0, 0, 0, 0);
            acc1 = __builtin_amdgcn_mfma_f32_16x16x32_f16(a_c, b1_c, acc1, 0, 0, 0);
            acc2 = __builtin_amdgcn_mfma_f32_16x16x32_f16(a_c, b2_c, acc2, 0, 0, 0);
            acc3 = __builtin_amdgcn_mfma_f32_16x16x32_f16(a_c, b3_c, acc3, 0, 0, 0);
            a_c = a_n; b0_c = b0_n; b1_c = b1_n; b2_c = b2_n; b3_c = b3_n;
        }
        // store: C row(n)=quad*4+r, col(m)=mi -> octet-blocked I (dense lines)
        const int n0 = row_base + quad * 4;
        const size_t obase = (size_t)(n0 >> 3) * (MTOT * 8) + (n0 & 7);
        #pragma unroll
        for (int u = 0; u < 4; ++u) {
            if (!val[u]) continue;
            const f32x4 a = u == 0 ? acc0 : u == 1 ? acc1 : u == 2 ? acc2 : acc3;
            half4_t h;
            #pragma unroll
            for (int r = 0; r < 4; ++r) h[r] = (_Float16)a[r];
            *(half4_t*)(I + obase + (size_t)(mt[u] * 16 + mi) * 8) = h;
        }
    }
}

// ---------------- LIF scan: sequential in t, parallel over (n,b) ----------
__global__ __launch_bounds__(256, 4) void snn_scan_kernel(
    const _Float16* __restrict__ I, const float* __restrict__ bias,
    _Float16* __restrict__ spk_out, float* __restrict__ out,
    const int nshift, const int is_last)
{
    const int gid = blockIdx.x * 256 + threadIdx.x;   // [0, 32<<nshift)
    const int N = 1 << nshift;
    const int n = gid & (N - 1);
    const int b = gid >> nshift;
    const float bi = bias[n];
    const size_t nbase = (size_t)(n >> 3) * (MTOT * 8) + (n & 7);
    float mem = 0.f, syn = 0.f, osum = 0.f, cnt = 0.f;
    #pragma unroll 4
    for (int t = 0; t < T_STEPS; ++t) {
        const int m = t * 32 + b;
        const float Iv = (float)I[nbase + (size_t)m * 8] + bi;
        syn = syn + (-syn / 5.0f + Iv);
        mem = mem + (-mem / 20.0f + syn);
        const float sv = (mem >= 1.0f) ? 1.0f : 0.0f;
        mem = (sv != 0.0f) ? 0.0f : mem;       // reset
        mem = (mem > 0.0f) ? mem : 0.0f;       // clamp negatives
        cnt += sv; osum += sv;
        if (!is_last) spk_out[nbase + (size_t)m * 8] = (_Float16)sv;
    }
    if (is_last) out[b * 512 + n] = osum * 0.01f;    // mean over T
    float c = cnt;
    #pragma unroll
    for (int s2 = 1; s2 < 64; s2 <<= 1) c += __shfl_xor(c, s2);
    if ((threadIdx.x & 63) == 0) atomicAdd(&out[16384], c);
}

extern "C" void kernel_launch(void* const* d_in, const int* in_sizes, int n_in,
                              void* d_out, int out_size, void* d_ws, size_t ws_size,
                              hipStream_t stream) {
    // setup_inputs() dict order: x, noise, time_steps, W0, b0, W1, b1, W2, b2
    const float* x     = (const float*)d_in[0];
    const float* noise = (const float*)d_in[1];
    const float* W0 = (const float*)d_in[3];
    const float* b0 = (const float*)d_in[4];
    const float* W1 = (const float*)d_in[5];
    const float* b1 = (const float*)d_in[6];
    const float* W2 = (const float*)d_in[7];
    const float* b2 = (const float*)d_in[8];
    float* out = (float*)d_out;

    _Float16* R0 = (_Float16*)((char*)d_ws + R0_OFF);
    _Float16* R1 = (_Float16*)((char*)d_ws + R1_OFF);
    _Float16* Ib = (_Float16*)((char*)d_ws + I_OFF);

    snn_encode_kernel<<<dim3(200), dim3(256), 0, stream>>>(x, noise, R0, out);

    snn_convw_kernel<<<dim3(2048), dim3(256), 0, stream>>>(W0, R1);
    snn_gemm_kernel<2048, 4><<<dim3(512), dim3(512), 0, stream>>>(R1, R0, Ib);
    snn_scan_kernel<<<dim3(256), dim3(256), 0, stream>>>(Ib, b0, R1, out, 11, 0);

    snn_convw_kernel<<<dim3(2048), dim3(256), 0, stream>>>(W1, R0);
    snn_gemm_kernel<2048, 4><<<dim3(512), dim3(512), 0, stream>>>(R0, R1, Ib);
    snn_scan_kernel<<<dim3(256), dim3(256), 0, stream>>>(Ib, b1, R0, out, 11, 0);

    snn_convw_kernel<<<dim3(512), dim3(256), 0, stream>>>(W2, R1);
    snn_gemm_kernel<512, 16><<<dim3(512), dim3(512), 0, stream>>>(R1, R0, Ib);
    snn_scan_kernel<<<dim3(64), dim3(256), 0, stream>>>(Ib, b2, nullptr, out, 9, 1);

    (void)in_sizes; (void)n_in; (void)out_size; (void)ws_size;
}

// Round 10
// 292.782 us; speedup vs baseline: 11.4992x; 1.4766x over previous
//
#include <hip/hip_runtime.h>

// SNN 2048->2048->2048->512, T=100, batch 32, LIF.
// Per layer: big GEMM over all t (M=3200=T*32) + sequential LIF scan.
// 7 stream-ordered launches, no grid sync.
//
// Unified "octet-blocked" layout (pitch MTOT) for spikes AND I:
//   half_idx(v, m) = ((v>>3)*MTOT + m)*8 + (v&7)     v = feature index
// Wave B-frag load at ((kb*4+quad)*MTOT + m0+mi)*8 yields
//   B[k=kb*32+quad*8+j][n=m0+mi]   (proven rounds 6-9).
//
// ws regions (total 39,321,600 B -- PROVEN available in round 7):
//   R0 [0,13107200) | R1 [+13107200) | I [+26214400)
// Schedule (region liveness verified):
//   fuse{enc->R0, convW0->R1} | gemm0(R1,R0->I) | fuse{scan0 I->R1, convW1->R0}
//   | gemm1(R0,R1->I) | fuse{scan1 I->R0, convW2->R1} | gemm2(R1,R0->I)
//   | scan2(I->out)
#define T_STEPS 100
#define MTOT    3200
#define R0_OFF  0
#define R1_OFF  13107200
#define I_OFF   26214400

typedef _Float16 half8_t __attribute__((ext_vector_type(8)));
typedef _Float16 half4_t __attribute__((ext_vector_type(4)));
typedef float    f32x4   __attribute__((ext_vector_type(4)));

// ---------------- encode (device fn): Poisson spikes for all t ----------
__device__ __forceinline__ void encode_body(
    int blk, const float* __restrict__ x, const float* __restrict__ noise,
    _Float16* __restrict__ spk0, float* __restrict__ out)
{
    if (blk == 0 && threadIdx.x == 0) out[16384] = 0.0f;  // runs first
    const int tid = threadIdx.x;
    const int m0  = blk * 16;
    __shared__ half8_t lds[16 * 257];    // pad: store-phase reads conflict-free
    #pragma unroll
    for (int ml = 0; ml < 16; ++ml) {    // read phase: thread = feature octet
        const int m = m0 + ml;
        const int t = m >> 5, b = m & 31;
        const float4 x1 = *(const float4*)(x + b * 2048 + tid * 8);
        const float4 x2 = *(const float4*)(x + b * 2048 + tid * 8 + 4);
        const float4 n1 = *(const float4*)(noise + (size_t)t * 65536 + b * 2048 + tid * 8);
        const float4 n2 = *(const float4*)(noise + (size_t)t * 65536 + b * 2048 + tid * 8 + 4);
        const float xr[8] = {x1.x,x1.y,x1.z,x1.w,x2.x,x2.y,x2.z,x2.w};
        const float nz[8] = {n1.x,n1.y,n1.z,n1.w,n2.x,n2.y,n2.z,n2.w};
        half8_t sp;
        #pragma unroll
        for (int j = 0; j < 8; ++j) {
            const float r = fminf(fmaxf(xr[j], 0.0f), 1.0f);
            sp[j] = (nz[j] < r) ? (_Float16)1.0f : (_Float16)0.0f;
        }
        lds[ml * 257 + tid] = sp;
    }
    __syncthreads();
    #pragma unroll
    for (int r = 0; r < 16; ++r) {       // store phase: lanes = consecutive m
        const int ml  = tid & 15;
        const int oct = r * 16 + (tid >> 4);
        *(half8_t*)(spk0 + ((size_t)oct * MTOT + m0 + ml) * 8) = lds[ml * 257 + oct];
    }
}

// ------------- convw (device fn): W fp32 -> fp16 A-frag swizzled ---------
// Wf[(row>>4)*32768 + ((koct>>2)*64 + (koct&3)*16 + (row&15))*8 + j]
//   = W[row][koct*8+j];  8 rows per block.
__device__ __forceinline__ void convw_body(
    int blk, const float* __restrict__ W, _Float16* __restrict__ Wf)
{
    const int koct = threadIdx.x;        // 0..255
    #pragma unroll
    for (int r = 0; r < 8; ++r) {
        const int row = blk * 8 + r;
        const float* wp = W + (size_t)row * 2048 + koct * 8;
        const float4 f1 = *(const float4*)(wp);
        const float4 f2 = *(const float4*)(wp + 4);
        half8_t h = {(_Float16)f1.x,(_Float16)f1.y,(_Float16)f1.z,(_Float16)f1.w,
                     (_Float16)f2.x,(_Float16)f2.y,(_Float16)f2.z,(_Float16)f2.w};
        const size_t idx = (size_t)(row >> 4) * 32768
                         + ((size_t)((koct >> 2) * 64 + (koct & 3) * 16 + (row & 15))) * 8;
        *(half8_t*)(Wf + idx) = h;
    }
}

// ------------- scan (device fn): LIF, sequential t, parallel (n,b) -------
__device__ __forceinline__ void scan_body(
    int blk, const _Float16* __restrict__ I, const float* __restrict__ bias,
    _Float16* __restrict__ spk_out, float* __restrict__ out,
    const int nshift, const int is_last)
{
    const int gid = blk * 256 + threadIdx.x;     // [0, 32<<nshift)
    const int N = 1 << nshift;
    const int n = gid & (N - 1);
    const int b = gid >> nshift;
    const float bi = bias[n];
    const size_t nbase = (size_t)(n >> 3) * (MTOT * 8) + (n & 7);
    float mem = 0.f, syn = 0.f, osum = 0.f, cnt = 0.f;
    #pragma unroll 4
    for (int t = 0; t < T_STEPS; ++t) {
        const int m = t * 32 + b;
        const float Iv = (float)I[nbase + (size_t)m * 8] + bi;
        syn = syn + (-syn / 5.0f + Iv);
        mem = mem + (-mem / 20.0f + syn);
        const float sv = (mem >= 1.0f) ? 1.0f : 0.0f;
        mem = (sv != 0.0f) ? 0.0f : mem;       // reset
        mem = (mem > 0.0f) ? mem : 0.0f;       // clamp negatives
        cnt += sv; osum += sv;
        if (!is_last) spk_out[nbase + (size_t)m * 8] = (_Float16)sv;
    }
    if (is_last) out[b * 512 + n] = osum * 0.01f;    // mean over T
    float c = cnt;
    #pragma unroll
    for (int s2 = 1; s2 < 64; s2 <<= 1) c += __shfl_xor(c, s2);
    if ((threadIdx.x & 63) == 0) atomicAdd(&out[16384], c);
}

// ---------------- fused small kernels (all 256 thr) ----------------
__global__ __launch_bounds__(256, 2) void snn_enc_convw_kernel(
    const float* __restrict__ x, const float* __restrict__ noise,
    _Float16* __restrict__ spk0, float* __restrict__ out,
    const float* __restrict__ W, _Float16* __restrict__ Wf)
{
    if (blockIdx.x < 200) encode_body(blockIdx.x, x, noise, spk0, out);
    else                  convw_body(blockIdx.x - 200, W, Wf);
}

__global__ __launch_bounds__(256, 4) void snn_scan_convw_kernel(
    const _Float16* __restrict__ I, const float* __restrict__ bias,
    _Float16* __restrict__ spk_out, float* __restrict__ out,
    const int scan_blocks, const int nshift,
    const float* __restrict__ W, _Float16* __restrict__ Wf)
{
    if ((int)blockIdx.x < scan_blocks)
        scan_body(blockIdx.x, I, bias, spk_out, out, nshift, 0);
    else
        convw_body(blockIdx.x - scan_blocks, W, Wf);
}

__global__ __launch_bounds__(256, 4) void snn_scan_kernel(
    const _Float16* __restrict__ I, const float* __restrict__ bias,
    float* __restrict__ out, const int nshift)
{
    scan_body(blockIdx.x, I, bias, nullptr, out, nshift, 1);
}

// ---------------- GEMM: I = spk @ W^T (fp16 MFMA 16x16x32) ----------------
// Block: 32 N-rows (two A subtiles, 128KB LDS), 1024 thr = 16 waves.
// Wave: TPW m-tiles x 2 n-subtiles accumulators; next-kb B prefetch.
// Each B load feeds 2 MFMAs (halves L2 B-traffic vs round 9).
// Grid: nbb x NC chunks, chunk = blk % NC aligns with XCD (blk % 8).
template<int NC, int TPW>
__global__ __launch_bounds__(1024, 4) void snn_gemm_kernel(
    const _Float16* __restrict__ Wf, const _Float16* __restrict__ spk,
    _Float16* __restrict__ I)
{
    const int tid  = threadIdx.x;
    const int lane = tid & 63;
    const int w    = tid >> 6;            // wave 0..15
    const int quad = lane >> 4, mi = lane & 15;
    const int chunk = blockIdx.x % NC;
    const int nbb   = blockIdx.x / NC;
    const int row_base = nbb * 32;
    const int jcount = (200 - chunk + NC - 1) / NC;   // 16-m-tiles in chunk

    __shared__ _Float16 wlds[32 * 2048];              // 128 KB, A-frag order
    {   // contiguous copy: Wf 16-row groups 2*nbb, 2*nbb+1
        const half8_t* __restrict__ src = (const half8_t*)(Wf + (size_t)nbb * 65536);
        half8_t* __restrict__ dst = (half8_t*)wlds;
        #pragma unroll
        for (int r = 0; r < 8; ++r) dst[tid + r * 1024] = src[tid + r * 1024];
    }
    __syncthreads();

    for (int jl0 = TPW * w; jl0 < jcount; jl0 += 16 * TPW) {
        int mt[TPW]; bool val[TPW];
        const _Float16* bp[TPW];
        #pragma unroll
        for (int u = 0; u < TPW; ++u) {
            const int jl = jl0 + u;
            val[u] = jl < jcount;
            mt[u]  = chunk + NC * (val[u] ? jl : jl0);
            bp[u]  = spk + ((size_t)mt[u] * 16 + mi) * 8;
        }
        f32x4 acc[TPW][2];
        #pragma unroll
        for (int u = 0; u < TPW; ++u) { acc[u][0] = (f32x4){0,0,0,0}; acc[u][1] = (f32x4){0,0,0,0}; }

        half8_t bc[TPW];
        const size_t k0 = (size_t)quad * (MTOT * 8);
        #pragma unroll
        for (int u = 0; u < TPW; ++u) bc[u] = *(const half8_t*)(bp[u] + k0);

        #pragma unroll 4
        for (int kb = 0; kb < 64; ++kb) {
            half8_t bn[TPW];
            if (kb < 63) {
                const size_t kn = (size_t)((kb + 1) * 4 + quad) * (MTOT * 8);
                #pragma unroll
                for (int u = 0; u < TPW; ++u) bn[u] = *(const half8_t*)(bp[u] + kn);
            }
            const half8_t a0 = *(const half8_t*)(wlds + ((size_t)(kb * 64 + lane)) * 8);
            const half8_t a1 = *(const half8_t*)(wlds + 32768 + ((size_t)(kb * 64 + lane)) * 8);
            #pragma unroll
            for (int u = 0; u < TPW; ++u) {
                acc[u][0] = __builtin_amdgcn_mfma_f32_16x16x32_f16(a0, bc[u], acc[u][0], 0, 0, 0);
                acc[u][1] = __builtin_amdgcn_mfma_f32_16x16x32_f16(a1, bc[u], acc[u][1], 0, 0, 0);
            }
            #pragma unroll
            for (int u = 0; u < TPW; ++u) bc[u] = bn[u];
        }
        // store: C row(n)=quad*4+r, col(m)=mi -> octet-blocked I
        #pragma unroll
        for (int s = 0; s < 2; ++s) {
            const int n0 = row_base + s * 16 + quad * 4;
            const size_t obase = (size_t)(n0 >> 3) * (MTOT * 8) + (n0 & 7);
            #pragma unroll
            for (int u = 0; u < TPW; ++u) {
                if (!val[u]) continue;
                half4_t h;
                #pragma unroll
                for (int r = 0; r < 4; ++r) h[r] = (_Float16)acc[u][s][r];
                *(half4_t*)(I + obase + (size_t)(mt[u] * 16 + mi) * 8) = h;
            }
        }
    }
}

extern "C" void kernel_launch(void* const* d_in, const int* in_sizes, int n_in,
                              void* d_out, int out_size, void* d_ws, size_t ws_size,
                              hipStream_t stream) {
    // setup_inputs() dict order: x, noise, time_steps, W0, b0, W1, b1, W2, b2
    const float* x     = (const float*)d_in[0];
    const float* noise = (const float*)d_in[1];
    const float* W0 = (const float*)d_in[3];
    const float* b0 = (const float*)d_in[4];
    const float* W1 = (const float*)d_in[5];
    const float* b1 = (const float*)d_in[6];
    const float* W2 = (const float*)d_in[7];
    const float* b2 = (const float*)d_in[8];
    float* out = (float*)d_out;

    _Float16* R0 = (_Float16*)((char*)d_ws + R0_OFF);
    _Float16* R1 = (_Float16*)((char*)d_ws + R1_OFF);
    _Float16* Ib = (_Float16*)((char*)d_ws + I_OFF);

    // encode -> R0 ; convW0 -> R1
    snn_enc_convw_kernel<<<dim3(456), dim3(256), 0, stream>>>(x, noise, R0, out, W0, R1);
    // gemm0: 64 nbb x 4 chunks = 256 blocks
    snn_gemm_kernel<4, 4><<<dim3(256), dim3(1024), 0, stream>>>(R1, R0, Ib);
    // scan0 (I->R1, 256 blocks) ; convW1 -> R0 (256 blocks)
    snn_scan_convw_kernel<<<dim3(512), dim3(256), 0, stream>>>(Ib, b0, R1, out, 256, 11, W1, R0);
    // gemm1
    snn_gemm_kernel<4, 4><<<dim3(256), dim3(1024), 0, stream>>>(R0, R1, Ib);
    // scan1 (I->R0, 256 blocks) ; convW2 -> R1 (64 blocks)
    snn_scan_convw_kernel<<<dim3(320), dim3(256), 0, stream>>>(Ib, b1, R0, out, 256, 11, W2, R1);
    // gemm2: 16 nbb x 16 chunks = 256 blocks, 1 tile/wave
    snn_gemm_kernel<16, 1><<<dim3(256), dim3(1024), 0, stream>>>(R1, R0, Ib);
    // scan2 -> out
    snn_scan_kernel<<<dim3(64), dim3(256), 0, stream>>>(Ib, b2, out, 9);

    (void)in_sizes; (void)n_in; (void)out_size; (void)ws_size;
}